// Round 2
// baseline (541.184 us; speedup 1.0000x reference)
//
#include <hip/hip_runtime.h>
#include <stdint.h>

#define N_TOK 4096
#define DIM   2048
#define NH    16
#define HD    128
#define NW    (DIM * DIM)

using bf16x8 = __attribute__((ext_vector_type(8))) short;
using bf16x4 = __attribute__((ext_vector_type(4))) short;
using f32x4  = __attribute__((ext_vector_type(4))) float;
using u32x2  = __attribute__((ext_vector_type(2))) unsigned int;

#if __has_builtin(__builtin_amdgcn_exp2f)
#define EXP2(x) __builtin_amdgcn_exp2f(x)
#else
#define EXP2(x) exp2f(x)
#endif

__device__ inline unsigned short f2bf(float f) {
  union { float f; unsigned u; } v; v.f = f;
  unsigned r = v.u + 0x7FFFu + ((v.u >> 16) & 1u);
  return (unsigned short)(r >> 16);
}
__device__ inline float bf2f(unsigned short u) {
  union { unsigned u; float f; } v; v.u = ((unsigned)u) << 16; return v.f;
}
__device__ inline f32x4 mfma16(bf16x8 a, bf16x8 b, f32x4 c) {
  return __builtin_amdgcn_mfma_f32_16x16x32_bf16(a, b, c, 0, 0, 0);
}
// async global->LDS, 16B per lane; LDS dest = wave-uniform base + lane*16
__device__ inline void gll16(const unsigned short* g, unsigned short* l) {
  __builtin_amdgcn_global_load_lds(
      (const __attribute__((address_space(1))) void*)g,
      (__attribute__((address_space(3))) void*)l, 16, 0, 0);
}

// pack two f32 -> one u32 of 2x bf16 (RNE). No builtin on gfx950 (guide T12).
__device__ inline unsigned cvtpk_bf16(float lo, float hi) {
  unsigned r;
  asm("v_cvt_pk_bf16_f32 %0, %1, %2" : "=v"(r) : "v"(lo), "v"(hi));
  return r;
}

// permlane swaps (gfx950). ret.x = {A.lo16/32-groups..}, see call sites.
__device__ inline u32x2 pl32swap(unsigned a, unsigned b) {
#if __has_builtin(__builtin_amdgcn_permlane32_swap)
  return __builtin_amdgcn_permlane32_swap(a, b, false, false);
#else
  int lane = threadIdx.x & 63;
  unsigned as = (unsigned)__shfl_xor((int)a, 32);
  unsigned bs = (unsigned)__shfl_xor((int)b, 32);
  u32x2 r;
  r.x = (lane & 32) ? bs : a;   // {A.lo32, B.lo32}
  r.y = (lane & 32) ? b : as;   // {A.hi32, B.hi32}
  return r;
#endif
}
__device__ inline u32x2 pl16swap(unsigned a, unsigned b) {
#if __has_builtin(__builtin_amdgcn_permlane16_swap)
  return __builtin_amdgcn_permlane16_swap(a, b, false, false);
#else
  int lane = threadIdx.x & 63;
  unsigned as = (unsigned)__shfl_xor((int)a, 16);
  unsigned bs = (unsigned)__shfl_xor((int)b, 16);
  u32x2 r;
  r.x = (lane & 16) ? bs : a;   // {A.g0, B.g0, A.g2, B.g2} (16-lane groups)
  r.y = (lane & 16) ? b : as;   // {A.g1, B.g1, A.g3, B.g3}
  return r;
#endif
}

// fp32 -> bf16 convert, 8 elems/thread
__global__ __launch_bounds__(256)
void cvt_bf16(const float* __restrict__ src, unsigned short* __restrict__ dst, int n) {
  int i = blockIdx.x * 256 + threadIdx.x;
  if (i * 8 >= n) return;
  const float4* s = (const float4*)src + (size_t)i * 2;
  float4 a = s[0], b = s[1];
  bf16x8 o;
  o[0] = (short)f2bf(a.x); o[1] = (short)f2bf(a.y);
  o[2] = (short)f2bf(a.z); o[3] = (short)f2bf(a.w);
  o[4] = (short)f2bf(b.x); o[5] = (short)f2bf(b.y);
  o[6] = (short)f2bf(b.z); o[7] = (short)f2bf(b.w);
  *(bf16x8*)(dst + (size_t)i * 8) = o;
}

// C[4096,2048] = A[4096,2048] @ B[2048,2048]^T (+bias)*scale; all-bf16 inputs.
// m97 structure: global_load_lds width=16 into unpadded LDS, 128x128 tile.
// OUT_MODE: 0 = bf16 row-major, 1 = fp32 row-major, 2 = bf16 transposed (Vt)
template<int OUT_MODE>
__global__ __launch_bounds__(256)
void gemm_bf16(const unsigned short* __restrict__ A, const unsigned short* __restrict__ B,
               const float* __restrict__ bias, void* __restrict__ out_, float scale) {
  __shared__ unsigned short Asl[128 * 32];
  __shared__ unsigned short Bsl[128 * 32];
  const int tid  = threadIdx.x;
  const int lane = tid & 63, w = tid >> 6;
  const int wy = w >> 1, wx = w & 1;
  const int lr = lane & 15, quad = lane >> 4;
  const int m0 = blockIdx.y * 128, n0 = blockIdx.x * 128;

  const f32x4 vzero = {0.f, 0.f, 0.f, 0.f};
  f32x4 acc[4][4];
#pragma unroll
  for (int i = 0; i < 4; ++i)
#pragma unroll
    for (int j = 0; j < 4; ++j) acc[i][j] = vzero;

  for (int k0 = 0; k0 < DIM; k0 += 32) {
    __syncthreads();
#pragma unroll
    for (int i = 0; i < 2; ++i) {
      int ch = tid + i * 256;            // 0..511 chunks of 16B
      int r = ch >> 2, cc = ch & 3;      // 128 rows x 4 chunks
      gll16(&A[(size_t)(m0 + r) * DIM + k0 + cc * 8], &Asl[ch * 8]);
      gll16(&B[(size_t)(n0 + r) * DIM + k0 + cc * 8], &Bsl[ch * 8]);
    }
    __syncthreads();

    bf16x8 af[4], bfv[4];
#pragma unroll
    for (int mb = 0; mb < 4; ++mb)
      af[mb] = *(const bf16x8*)&Asl[(wy * 64 + mb * 16 + lr) * 32 + quad * 8];
#pragma unroll
    for (int nb = 0; nb < 4; ++nb)
      bfv[nb] = *(const bf16x8*)&Bsl[(wx * 64 + nb * 16 + lr) * 32 + quad * 8];
#pragma unroll
    for (int mb = 0; mb < 4; ++mb)
#pragma unroll
      for (int nb = 0; nb < 4; ++nb)
        acc[mb][nb] = mfma16(af[mb], bfv[nb], acc[mb][nb]);
  }

#pragma unroll
  for (int mb = 0; mb < 4; ++mb)
#pragma unroll
    for (int nb = 0; nb < 4; ++nb) {
      int gn = n0 + wx * 64 + nb * 16 + lr;
      int gm_base = m0 + wy * 64 + mb * 16 + quad * 4;
      float bs = bias[gn];
      if constexpr (OUT_MODE == 2) {
        bf16x4 pk;
#pragma unroll
        for (int r = 0; r < 4; ++r) pk[r] = (short)f2bf((acc[mb][nb][r] + bs) * scale);
        *(bf16x4*)&((unsigned short*)out_)[(size_t)gn * N_TOK + gm_base] = pk;
      } else {
#pragma unroll
        for (int r = 0; r < 4; ++r) {
          float v = (acc[mb][nb][r] + bs) * scale;
          if constexpr (OUT_MODE == 1)
            ((float*)out_)[(size_t)(gm_base + r) * DIM + gn] = v;
          else
            ((unsigned short*)out_)[(size_t)(gm_base + r) * DIM + gn] = f2bf(v);
        }
      }
    }
}

// Flash attention, no-max softmax (scores bounded; exp2 domain folded into Q).
// Block = 128 q-rows x 1 head; 4 waves x 32 rows; 64-key tiles; V pre-transposed.
// Swapped QK^T (mfma(K,Q)) -> softmax fully in registers (cvt_pk + permlane).
// Staggered pipeline: iteration kt issues QK(kt) and PV(kt-1) as one MFMA
// cluster (no VALU dependency between them), softmax(kt) after. V double-buffered.
__global__ __launch_bounds__(256)
void flash_attn(const unsigned short* __restrict__ Q,
                const unsigned short* __restrict__ K,
                const unsigned short* __restrict__ Vt,
                unsigned short* __restrict__ ctx) {
  constexpr int LDK = 136;  // K tile row stride (128+8)
  constexpr int LDV = 72;   // Vt tile row stride (64+8)
  constexpr int NT  = N_TOK / 64;
  __shared__ unsigned short Ksl[64 * LDK];
  __shared__ unsigned short VTsl[2][128 * LDV];

  const int tid  = threadIdx.x;
  const int lane = tid & 63, w = tid >> 6;
  const int lr = lane & 15, quad = lane >> 4;
  const int hoff = blockIdx.y * HD;
  const int q0   = blockIdx.x * 128;
  const int qw   = q0 + w * 32;

  // Q fragments; L2E/sqrt(128) already folded in at projection.
  bf16x8 qf[2][4];
#pragma unroll
  for (int mb = 0; mb < 2; ++mb)
#pragma unroll
    for (int c = 0; c < 4; ++c)
      qf[mb][c] = *(const bf16x8*)&Q[(size_t)(qw + mb * 16 + lr) * DIM + hoff + c * 32 + quad * 8];

  const f32x4 vzero = {0.f, 0.f, 0.f, 0.f};
  f32x4 o[2][8];
  float l_acc[2] = {0.f, 0.f};  // row-sum for q-row = lr (per mb group)
#pragma unroll
  for (int mb = 0; mb < 2; ++mb)
#pragma unroll
    for (int nb = 0; nb < 8; ++nb) o[mb][nb] = vzero;

  bf16x8 kreg[4], vreg[4];
  auto load_tile = [&](int kt) {
    int kbase = kt * 64;
#pragma unroll
    for (int i = 0; i < 4; ++i) {
      int ch = tid + i * 256;
      kreg[i] = *(const bf16x8*)&K[(size_t)(kbase + (ch >> 4)) * DIM + hoff + (ch & 15) * 8];
      vreg[i] = *(const bf16x8*)&Vt[(size_t)(hoff + (ch >> 3)) * N_TOK + kbase + (ch & 7) * 8];
    }
  };
  auto stage = [&](int buf) {
#pragma unroll
    for (int i = 0; i < 4; ++i) {
      int ch = tid + i * 256;
      *(bf16x8*)&Ksl[(ch >> 4) * LDK + (ch & 15) * 8] = kreg[i];
      *(bf16x8*)&VTsl[buf][(ch >> 3) * LDV + (ch & 7) * 8] = vreg[i];
    }
  };

  f32x4 s[2][4];
  bf16x8 pf[2][2];

  // S^T = K @ Q^T : lane holds S[q = mb*16+lr][key = nf*16 + quad*4 + r]
  auto qk = [&]() {
#pragma unroll
    for (int mb = 0; mb < 2; ++mb)
#pragma unroll
      for (int nf = 0; nf < 4; ++nf) s[mb][nf] = vzero;
#pragma unroll
    for (int nf = 0; nf < 4; ++nf)
#pragma unroll
      for (int c = 0; c < 4; ++c) {
        bf16x8 kf = *(const bf16x8*)&Ksl[(nf * 16 + lr) * LDK + c * 32 + quad * 8];
#pragma unroll
        for (int mb = 0; mb < 2; ++mb) s[mb][nf] = mfma16(kf, qf[mb][c], s[mb][nf]);
      }
  };

  // O += P @ V (pf from softmax of the matching tile)
  auto pv = [&](int buf) {
#pragma unroll
    for (int nb = 0; nb < 8; ++nb)
#pragma unroll
      for (int ki = 0; ki < 2; ++ki) {
        bf16x8 vf = *(const bf16x8*)&VTsl[buf][(nb * 16 + lr) * LDV + ki * 32 + quad * 8];
#pragma unroll
        for (int mb = 0; mb < 2; ++mb) o[mb][nb] = mfma16(pf[mb][ki], vf, o[mb][nb]);
      }
  };

  // In-register softmax + redistribution into PV A-fragments.
  // Target word t of pf[mb][ki] (lane quad q) = keys ki*32 + q*8 + {2t,2t+1}
  //   = source lane quad (q&1)*2 + (t>>1), W[2ki + (q>>1)][t&1].
  auto softmax = [&]() {
#pragma unroll
    for (int mb = 0; mb < 2; ++mb) {
      unsigned W[4][2];
      float lp = 0.f;
#pragma unroll
      for (int nf = 0; nf < 4; ++nf) {
        float e0 = EXP2(s[mb][nf][0]);
        float e1 = EXP2(s[mb][nf][1]);
        float e2 = EXP2(s[mb][nf][2]);
        float e3 = EXP2(s[mb][nf][3]);
        lp += (e0 + e1) + (e2 + e3);
        W[nf][0] = cvtpk_bf16(e0, e1);
        W[nf][1] = cvtpk_bf16(e2, e3);
      }
      l_acc[mb] += lp;
#pragma unroll
      for (int ki = 0; ki < 2; ++ki) {
        u32x2 a0  = pl32swap(W[2 * ki][0], W[2 * ki + 1][0]);
        u32x2 t02 = pl16swap(a0.x, a0.y);   // (T0, T2)
        u32x2 a1  = pl32swap(W[2 * ki][1], W[2 * ki + 1][1]);
        u32x2 t13 = pl16swap(a1.x, a1.y);   // (T1, T3)
        union { unsigned u[4]; bf16x8 v; } pu;
        pu.u[0] = t02.x; pu.u[1] = t13.x; pu.u[2] = t02.y; pu.u[3] = t13.y;
        pf[mb][ki] = pu.v;
      }
    }
  };

  // ---- peel kt = 0 ----
  load_tile(0);
  stage(0);                 // no prior readers; disjoint writes
  __syncthreads();
  load_tile(1);
  qk();
  softmax();

  // ---- steady state: QK(kt) + PV(kt-1) as one MFMA cluster ----
  for (int kt = 1; kt < NT; ++kt) {
    __syncthreads();        // all waves done reading Ksl(kt-1) and VTsl[kt&1] (PV(kt-2))
    stage(kt & 1);
    __syncthreads();
    if (kt + 1 < NT) load_tile(kt + 1);  // global->reg prefetch under compute
    __builtin_amdgcn_s_setprio(1);
    qk();                   // tile kt
    pv((kt - 1) & 1);       // tile kt-1, pf from previous softmax
    __builtin_amdgcn_s_setprio(0);
    softmax();              // tile kt -> new pf
  }
  pv((NT - 1) & 1);         // final tile's PV

  // Row-sums live at q-row = lr; reduce the 4 quad-slices, then transpose
  // to q = quad*4+r via shfl for the store.
#pragma unroll
  for (int mb = 0; mb < 2; ++mb) {
    float t = l_acc[mb];
    t += __shfl_xor(t, 16);
    t += __shfl_xor(t, 32);
    l_acc[mb] = t;  // all lanes: L[mb][lr]
  }
#pragma unroll
  for (int mb = 0; mb < 2; ++mb)
#pragma unroll
    for (int r = 0; r < 4; ++r) {
      float Lr = __shfl(l_acc[mb], quad * 4 + r);  // L for q-row quad*4+r
      float inv = 1.0f / Lr;
      int gq = qw + mb * 16 + quad * 4 + r;
#pragma unroll
      for (int nb = 0; nb < 8; ++nb)
        ctx[(size_t)gq * DIM + hoff + nb * 16 + lr] = f2bf(o[mb][nb][r] * inv);
    }
}

extern "C" void kernel_launch(void* const* d_in, const int* in_sizes, int n_in,
                              void* d_out, int out_size, void* d_ws, size_t ws_size,
                              hipStream_t stream) {
  (void)in_sizes; (void)n_in; (void)out_size; (void)ws_size;
  const float* x  = (const float*)d_in[0];
  const float* Wq = (const float*)d_in[1];
  const float* bq = (const float*)d_in[2];
  const float* Wk = (const float*)d_in[3];
  const float* bk = (const float*)d_in[4];
  const float* Wv = (const float*)d_in[5];
  const float* bv = (const float*)d_in[6];
  const float* Wo = (const float*)d_in[7];
  const float* bo = (const float*)d_in[8];

  const size_t NE = (size_t)N_TOK * DIM;  // 8.4M
  unsigned short* xb  = (unsigned short*)d_ws;      // also reused as ctx later
  unsigned short* Wqb = xb + NE;
  unsigned short* Wkb = Wqb + NW;
  unsigned short* Wvb = Wkb + NW;
  unsigned short* Wob = Wvb + NW;
  unsigned short* Qb  = Wob + NW;
  unsigned short* Kb  = Qb + NE;
  unsigned short* Vtb = Kb + NE;   // total ~100.7 MB

  cvt_bf16<<<4096, 256, 0, stream>>>(x,  xb,  (int)NE);
  cvt_bf16<<<2048, 256, 0, stream>>>(Wq, Wqb, NW);
  cvt_bf16<<<2048, 256, 0, stream>>>(Wk, Wkb, NW);
  cvt_bf16<<<2048, 256, 0, stream>>>(Wv, Wvb, NW);
  cvt_bf16<<<2048, 256, 0, stream>>>(Wo, Wob, NW);

  dim3 gemm_grid(DIM / 128, N_TOK / 128);  // (16, 32)
  // fold softmax scale AND log2(e) into Q so scores are already in exp2 domain
  const float qscale = 1.4426950408889634f * 0.08838834764831845f;

  gemm_bf16<0><<<gemm_grid, 256, 0, stream>>>(xb, Wqb, bq, Qb, qscale);
  gemm_bf16<0><<<gemm_grid, 256, 0, stream>>>(xb, Wkb, bk, Kb, 1.0f);
  gemm_bf16<2><<<gemm_grid, 256, 0, stream>>>(xb, Wvb, bv, Vtb, 1.0f);

  unsigned short* ctxb = xb;  // x dead after V projection; reuse
  flash_attn<<<dim3(N_TOK / 128, NH), 256, 0, stream>>>(Qb, Kb, Vtb, ctxb);

  gemm_bf16<1><<<gemm_grid, 256, 0, stream>>>(ctxb, Wob, bo, (float*)d_out, 1.0f);
}

// Round 3
// 491.142 us; speedup vs baseline: 1.1019x; 1.1019x over previous
//
#include <hip/hip_runtime.h>
#include <stdint.h>

#define N_TOK 4096
#define DIM   2048
#define NH    16
#define HD    128
#define NW    (DIM * DIM)

using bf16x8 = __attribute__((ext_vector_type(8))) short;
using bf16x4 = __attribute__((ext_vector_type(4))) short;
using f32x4  = __attribute__((ext_vector_type(4))) float;
using u32x2  = __attribute__((ext_vector_type(2))) unsigned int;

#if __has_builtin(__builtin_amdgcn_exp2f)
#define EXP2(x) __builtin_amdgcn_exp2f(x)
#else
#define EXP2(x) exp2f(x)
#endif

__device__ inline unsigned short f2bf(float f) {
  union { float f; unsigned u; } v; v.f = f;
  unsigned r = v.u + 0x7FFFu + ((v.u >> 16) & 1u);
  return (unsigned short)(r >> 16);
}
__device__ inline float bf2f(unsigned short u) {
  union { unsigned u; float f; } v; v.u = ((unsigned)u) << 16; return v.f;
}
__device__ inline f32x4 mfma16(bf16x8 a, bf16x8 b, f32x4 c) {
  return __builtin_amdgcn_mfma_f32_16x16x32_bf16(a, b, c, 0, 0, 0);
}
// async global->LDS, 16B per lane; LDS dest = wave-uniform base + lane*16
__device__ inline void gll16(const unsigned short* g, unsigned short* l) {
  __builtin_amdgcn_global_load_lds(
      (const __attribute__((address_space(1))) void*)g,
      (__attribute__((address_space(3))) void*)l, 16, 0, 0);
}

// pack two f32 -> one u32 of 2x bf16 (RNE). No builtin on gfx950 (guide T12).
__device__ inline unsigned cvtpk_bf16(float lo, float hi) {
  unsigned r;
  asm("v_cvt_pk_bf16_f32 %0, %1, %2" : "=v"(r) : "v"(lo), "v"(hi));
  return r;
}

// permlane swaps (gfx950). ret.x = {A.lo16/32-groups..}, see call sites.
__device__ inline u32x2 pl32swap(unsigned a, unsigned b) {
#if __has_builtin(__builtin_amdgcn_permlane32_swap)
  return __builtin_amdgcn_permlane32_swap(a, b, false, false);
#else
  int lane = threadIdx.x & 63;
  unsigned as = (unsigned)__shfl_xor((int)a, 32);
  unsigned bs = (unsigned)__shfl_xor((int)b, 32);
  u32x2 r;
  r.x = (lane & 32) ? bs : a;   // {A.lo32, B.lo32}
  r.y = (lane & 32) ? b : as;   // {A.hi32, B.hi32}
  return r;
#endif
}
__device__ inline u32x2 pl16swap(unsigned a, unsigned b) {
#if __has_builtin(__builtin_amdgcn_permlane16_swap)
  return __builtin_amdgcn_permlane16_swap(a, b, false, false);
#else
  int lane = threadIdx.x & 63;
  unsigned as = (unsigned)__shfl_xor((int)a, 16);
  unsigned bs = (unsigned)__shfl_xor((int)b, 16);
  u32x2 r;
  r.x = (lane & 16) ? bs : a;   // {A.g0, B.g0, A.g2, B.g2} (16-lane groups)
  r.y = (lane & 16) ? b : as;   // {A.g1, B.g1, A.g3, B.g3}
  return r;
#endif
}

// fp32 -> bf16 convert, 8 elems/thread
__global__ __launch_bounds__(256)
void cvt_bf16(const float* __restrict__ src, unsigned short* __restrict__ dst, int n) {
  int i = blockIdx.x * 256 + threadIdx.x;
  if (i * 8 >= n) return;
  const float4* s = (const float4*)src + (size_t)i * 2;
  float4 a = s[0], b = s[1];
  bf16x8 o;
  o[0] = (short)f2bf(a.x); o[1] = (short)f2bf(a.y);
  o[2] = (short)f2bf(a.z); o[3] = (short)f2bf(a.w);
  o[4] = (short)f2bf(b.x); o[5] = (short)f2bf(b.y);
  o[6] = (short)f2bf(b.z); o[7] = (short)f2bf(b.w);
  *(bf16x8*)(dst + (size_t)i * 8) = o;
}

// C[4096,2048] = A[4096,2048] @ B[2048,2048]^T (+bias)*scale; all-bf16 inputs.
// m97 structure: global_load_lds width=16 into unpadded LDS, 128x128 tile.
// OUT_MODE: 0 = bf16 row-major, 1 = fp32 row-major, 2 = bf16 transposed (Vt)
template<int OUT_MODE>
__global__ __launch_bounds__(256)
void gemm_bf16(const unsigned short* __restrict__ A, const unsigned short* __restrict__ B,
               const float* __restrict__ bias, void* __restrict__ out_, float scale) {
  __shared__ unsigned short Asl[128 * 32];
  __shared__ unsigned short Bsl[128 * 32];
  const int tid  = threadIdx.x;
  const int lane = tid & 63, w = tid >> 6;
  const int wy = w >> 1, wx = w & 1;
  const int lr = lane & 15, quad = lane >> 4;
  const int m0 = blockIdx.y * 128, n0 = blockIdx.x * 128;

  const f32x4 vzero = {0.f, 0.f, 0.f, 0.f};
  f32x4 acc[4][4];
#pragma unroll
  for (int i = 0; i < 4; ++i)
#pragma unroll
    for (int j = 0; j < 4; ++j) acc[i][j] = vzero;

  for (int k0 = 0; k0 < DIM; k0 += 32) {
    __syncthreads();
#pragma unroll
    for (int i = 0; i < 2; ++i) {
      int ch = tid + i * 256;            // 0..511 chunks of 16B
      int r = ch >> 2, cc = ch & 3;      // 128 rows x 4 chunks
      gll16(&A[(size_t)(m0 + r) * DIM + k0 + cc * 8], &Asl[ch * 8]);
      gll16(&B[(size_t)(n0 + r) * DIM + k0 + cc * 8], &Bsl[ch * 8]);
    }
    __syncthreads();

    bf16x8 af[4], bfv[4];
#pragma unroll
    for (int mb = 0; mb < 4; ++mb)
      af[mb] = *(const bf16x8*)&Asl[(wy * 64 + mb * 16 + lr) * 32 + quad * 8];
#pragma unroll
    for (int nb = 0; nb < 4; ++nb)
      bfv[nb] = *(const bf16x8*)&Bsl[(wx * 64 + nb * 16 + lr) * 32 + quad * 8];
#pragma unroll
    for (int mb = 0; mb < 4; ++mb)
#pragma unroll
      for (int nb = 0; nb < 4; ++nb)
        acc[mb][nb] = mfma16(af[mb], bfv[nb], acc[mb][nb]);
  }

#pragma unroll
  for (int mb = 0; mb < 4; ++mb)
#pragma unroll
    for (int nb = 0; nb < 4; ++nb) {
      int gn = n0 + wx * 64 + nb * 16 + lr;
      int gm_base = m0 + wy * 64 + mb * 16 + quad * 4;
      float bs = bias[gn];
      if constexpr (OUT_MODE == 2) {
        bf16x4 pk;
#pragma unroll
        for (int r = 0; r < 4; ++r) pk[r] = (short)f2bf((acc[mb][nb][r] + bs) * scale);
        *(bf16x4*)&((unsigned short*)out_)[(size_t)gn * N_TOK + gm_base] = pk;
      } else {
#pragma unroll
        for (int r = 0; r < 4; ++r) {
          float v = (acc[mb][nb][r] + bs) * scale;
          if constexpr (OUT_MODE == 1)
            ((float*)out_)[(size_t)(gm_base + r) * DIM + gn] = v;
          else
            ((unsigned short*)out_)[(size_t)(gm_base + r) * DIM + gn] = f2bf(v);
        }
      }
    }
}

// Flash attention, no-max softmax (scores bounded; exp2 domain folded into Q).
// LDS-BW-bound analysis (R2 post-mortem): K/V LDS reads are shared across a
// wave's q-rows, so doubling q-rows per wave (mb=4, 64 rows) halves LDS bytes
// per FLOP: 26 -> 52 FLOP/LDS-byte, crossing the 2.5PF/69TB/s balance point.
// Block = 256 q-rows x 1 head; 4 waves x 64 rows; 64-key tiles; 1 block/CU;
// ~340 VGPR -> 1 wave/SIMD (launch_bounds(256,1)).
// Swapped QK^T (mfma(K,Q)) -> softmax fully in registers (cvt_pk + permlane).
__global__ __launch_bounds__(256, 1)
void flash_attn(const unsigned short* __restrict__ Q,
                const unsigned short* __restrict__ K,
                const unsigned short* __restrict__ Vt,
                unsigned short* __restrict__ ctx) {
  constexpr int LDK = 136;  // K tile row stride (128+8)
  constexpr int LDV = 72;   // Vt tile row stride (64+8)
  constexpr int NT  = N_TOK / 64;
  __shared__ unsigned short Ksl[64 * LDK];
  __shared__ unsigned short VTsl[128 * LDV];

  const int tid  = threadIdx.x;
  const int lane = tid & 63, w = tid >> 6;
  const int lr = lane & 15, quad = lane >> 4;
  const int hoff = blockIdx.y * HD;
  const int q0   = blockIdx.x * 256;
  const int qw   = q0 + w * 64;

  // Q fragments; L2E/sqrt(128) already folded in at projection.
  // Layout [free=lr (q-row)][k=c*32+quad*8] = B-operand of swapped mfma(K,Q).
  bf16x8 qf[4][4];
#pragma unroll
  for (int mb = 0; mb < 4; ++mb)
#pragma unroll
    for (int c = 0; c < 4; ++c)
      qf[mb][c] = *(const bf16x8*)&Q[(size_t)(qw + mb * 16 + lr) * DIM + hoff + c * 32 + quad * 8];

  const f32x4 vzero = {0.f, 0.f, 0.f, 0.f};
  f32x4 o[4][8];
  float l_acc[4] = {0.f, 0.f, 0.f, 0.f};  // row-sum for q-row = lr (per mb)
#pragma unroll
  for (int mb = 0; mb < 4; ++mb)
#pragma unroll
    for (int nb = 0; nb < 8; ++nb) o[mb][nb] = vzero;

  bf16x8 kreg[4], vreg[4];
  auto load_tile = [&](int kt) {
    int kbase = kt * 64;
#pragma unroll
    for (int i = 0; i < 4; ++i) {
      int ch = tid + i * 256;
      kreg[i] = *(const bf16x8*)&K[(size_t)(kbase + (ch >> 4)) * DIM + hoff + (ch & 15) * 8];
      vreg[i] = *(const bf16x8*)&Vt[(size_t)(hoff + (ch >> 3)) * N_TOK + kbase + (ch & 7) * 8];
    }
  };
  load_tile(0);

  for (int kt = 0; kt < NT; ++kt) {
    __syncthreads();  // previous tile's LDS reads complete
#pragma unroll
    for (int i = 0; i < 4; ++i) {
      int ch = tid + i * 256;
      *(bf16x8*)&Ksl[(ch >> 4) * LDK + (ch & 15) * 8] = kreg[i];
      *(bf16x8*)&VTsl[(ch >> 3) * LDV + (ch & 7) * 8] = vreg[i];
    }
    __syncthreads();
    if (kt + 1 < NT) load_tile(kt + 1);  // global->reg prefetch under compute

    // S^T = K @ Q^T : lane holds S[q = mb*16+lr][key = nf*16 + quad*4 + r]
    f32x4 s[4][4];
#pragma unroll
    for (int mb = 0; mb < 4; ++mb)
#pragma unroll
      for (int nf = 0; nf < 4; ++nf) s[mb][nf] = vzero;
#pragma unroll
    for (int nf = 0; nf < 4; ++nf)
#pragma unroll
      for (int c = 0; c < 4; ++c) {
        bf16x8 kf = *(const bf16x8*)&Ksl[(nf * 16 + lr) * LDK + c * 32 + quad * 8];
#pragma unroll
        for (int mb = 0; mb < 4; ++mb) s[mb][nf] = mfma16(kf, qf[mb][c], s[mb][nf]);
      }

    // In-register softmax + redistribution into PV A-fragments.
    // Target word t of pf[mb][ki] (lane quad q) = keys ki*32 + q*8 + {2t,2t+1}
    //   = source lane quad (q&1)*2 + (t>>1), W[2ki + (q>>1)][t&1].
    bf16x8 pf[4][2];
#pragma unroll
    for (int mb = 0; mb < 4; ++mb) {
      unsigned W[4][2];
      float lp = 0.f;
#pragma unroll
      for (int nf = 0; nf < 4; ++nf) {
        float e0 = EXP2(s[mb][nf][0]);
        float e1 = EXP2(s[mb][nf][1]);
        float e2 = EXP2(s[mb][nf][2]);
        float e3 = EXP2(s[mb][nf][3]);
        lp += (e0 + e1) + (e2 + e3);
        W[nf][0] = cvtpk_bf16(e0, e1);
        W[nf][1] = cvtpk_bf16(e2, e3);
      }
      l_acc[mb] += lp;
#pragma unroll
      for (int ki = 0; ki < 2; ++ki) {
        u32x2 a0  = pl32swap(W[2 * ki][0], W[2 * ki + 1][0]);
        u32x2 t02 = pl16swap(a0.x, a0.y);   // (T0, T2)
        u32x2 a1  = pl32swap(W[2 * ki][1], W[2 * ki + 1][1]);
        u32x2 t13 = pl16swap(a1.x, a1.y);   // (T1, T3)
        union { unsigned u[4]; bf16x8 v; } pu;
        pu.u[0] = t02.x; pu.u[1] = t13.x; pu.u[2] = t02.y; pu.u[3] = t13.y;
        pf[mb][ki] = pu.v;
      }
    }

    // O += P @ V  (kf/vf reuse across 4 mb is the LDS-traffic win)
#pragma unroll
    for (int nb = 0; nb < 8; ++nb)
#pragma unroll
      for (int ki = 0; ki < 2; ++ki) {
        bf16x8 vf = *(const bf16x8*)&VTsl[(nb * 16 + lr) * LDV + ki * 32 + quad * 8];
#pragma unroll
        for (int mb = 0; mb < 4; ++mb) o[mb][nb] = mfma16(pf[mb][ki], vf, o[mb][nb]);
      }
  }

  // Row-sums live at q-row = lr; reduce the 4 quad-slices, then transpose
  // to q = quad*4+r via shfl for the store.
#pragma unroll
  for (int mb = 0; mb < 4; ++mb) {
    float t = l_acc[mb];
    t += __shfl_xor(t, 16);
    t += __shfl_xor(t, 32);
    l_acc[mb] = t;  // all lanes: L[mb][lr]
  }
#pragma unroll
  for (int mb = 0; mb < 4; ++mb)
#pragma unroll
    for (int r = 0; r < 4; ++r) {
      float Lr = __shfl(l_acc[mb], quad * 4 + r);  // L for q-row quad*4+r
      float inv = 1.0f / Lr;
      int gq = qw + mb * 16 + quad * 4 + r;
#pragma unroll
      for (int nb = 0; nb < 8; ++nb)
        ctx[(size_t)gq * DIM + hoff + nb * 16 + lr] = f2bf(o[mb][nb][r] * inv);
    }
}

extern "C" void kernel_launch(void* const* d_in, const int* in_sizes, int n_in,
                              void* d_out, int out_size, void* d_ws, size_t ws_size,
                              hipStream_t stream) {
  (void)in_sizes; (void)n_in; (void)out_size; (void)ws_size;
  const float* x  = (const float*)d_in[0];
  const float* Wq = (const float*)d_in[1];
  const float* bq = (const float*)d_in[2];
  const float* Wk = (const float*)d_in[3];
  const float* bk = (const float*)d_in[4];
  const float* Wv = (const float*)d_in[5];
  const float* bv = (const float*)d_in[6];
  const float* Wo = (const float*)d_in[7];
  const float* bo = (const float*)d_in[8];

  const size_t NE = (size_t)N_TOK * DIM;  // 8.4M
  unsigned short* xb  = (unsigned short*)d_ws;      // also reused as ctx later
  unsigned short* Wqb = xb + NE;
  unsigned short* Wkb = Wqb + NW;
  unsigned short* Wvb = Wkb + NW;
  unsigned short* Wob = Wvb + NW;
  unsigned short* Qb  = Wob + NW;
  unsigned short* Kb  = Qb + NE;
  unsigned short* Vtb = Kb + NE;   // total ~100.7 MB

  cvt_bf16<<<4096, 256, 0, stream>>>(x,  xb,  (int)NE);
  cvt_bf16<<<2048, 256, 0, stream>>>(Wq, Wqb, NW);
  cvt_bf16<<<2048, 256, 0, stream>>>(Wk, Wkb, NW);
  cvt_bf16<<<2048, 256, 0, stream>>>(Wv, Wvb, NW);
  cvt_bf16<<<2048, 256, 0, stream>>>(Wo, Wob, NW);

  dim3 gemm_grid(DIM / 128, N_TOK / 128);  // (16, 32)
  // fold softmax scale AND log2(e) into Q so scores are already in exp2 domain
  const float qscale = 1.4426950408889634f * 0.08838834764831845f;

  gemm_bf16<0><<<gemm_grid, 256, 0, stream>>>(xb, Wqb, bq, Qb, qscale);
  gemm_bf16<0><<<gemm_grid, 256, 0, stream>>>(xb, Wkb, bk, Kb, 1.0f);
  gemm_bf16<2><<<gemm_grid, 256, 0, stream>>>(xb, Wvb, bv, Vtb, 1.0f);

  unsigned short* ctxb = xb;  // x dead after V projection; reuse
  flash_attn<<<dim3(N_TOK / 256, NH), 256, 0, stream>>>(Qb, Kb, Vtb, ctxb);

  gemm_bf16<1><<<gemm_grid, 256, 0, stream>>>(ctxb, Wob, bo, (float*)d_out, 1.0f);
}